// Round 6
// baseline (282.906 us; speedup 1.0000x reference)
//
#include <hip/hip_runtime.h>
#include <hip/hip_bf16.h>
#include <cstdint>

#define B_N 64
#define C_N 2048
#define HW_N 196
#define HWP 224          // zero-padded hw length for A (7 k-steps of 32)
#define M_N 32
#define NC_N 396
#define K_N 65536        // M_N * C_N
#define CCH 128          // c-chunk per k1a block
#define NCH 16           // number of c-chunks
#define KCH 128          // k3 k-chunks (k-chunk = 512)
#define ZSTRIDE (B_N * M_N * HW_N)   // 401408 floats per chunk-partial

typedef __attribute__((ext_vector_type(8))) short bf16x8;
typedef __attribute__((ext_vector_type(4))) float f32x4;

__device__ inline short f2bf(float x) {   // RNE fp32 -> bf16
  union { float f; unsigned u; } v; v.f = x;
  unsigned r = (v.u + 0x7FFFu + ((v.u >> 16) & 1u)) >> 16;
  return (short)r;
}

__device__ inline unsigned packbf2(float lo, float hi) {  // lo -> low 16 bits
  return ((unsigned)(unsigned short)f2bf(hi) << 16) |
         (unsigned)(unsigned short)f2bf(lo);
}

// ---------------------------------------------------------------------------
// K1a: z[cx][b][m][hw] = sum_{c in chunk cx} x[b][c][hw] * Wa[m][c]
// grid(16,64), block 256 (4 waves). CCH=128 -> 1024 blocks = 4 blocks/CU
// (16 waves/CU) for latency hiding; LDS trimmed to 40KB (xT has no pad rows;
// the ht=12 tail rows >=196 are masked with a lane select). Double-buffered
// xT: stage ss+1's global loads issue before stage ss's MFMAs.
// ---------------------------------------------------------------------------
__global__ __launch_bounds__(256) void k1a_partial(
    const float* __restrict__ x, const float* __restrict__ Wa,
    float* __restrict__ z) {
  __shared__ short waT[32][136];      // Wa chunk bf16, row stride 272B (pad +8)
  __shared__ short xT[2][196][40];    // x^T stages [hw][c'] bf16, stride 80B
  const int t = threadIdx.x;
  const int w = t >> 6, lane = t & 63, lq = lane >> 4, ln = lane & 15;
  const int cx = blockIdx.x, b = blockIdx.y;
  const int c0 = cx * CCH;

  unsigned* xTw0 = (unsigned*)xT[0];
  unsigned* xTw1 = (unsigned*)xT[1];
  // stage Wa[0:32][c0:c0+128] -> waT (bf16), coalesced row-major reads
  for (int i = t; i < 1024; i += 256) {
    int m = i >> 5, f4 = i & 31;
    float4 v = *(const float4*)(Wa + (size_t)m * C_N + c0 + f4 * 4);
    uint2 pk;
    pk.x = packbf2(v.x, v.y);
    pk.y = packbf2(v.z, v.w);
    *(uint2*)((char*)waT + m * 272 + f4 * 8) = pk;
  }

  f32x4 acc[4][2];
#pragma unroll
  for (int ti = 0; ti < 4; ++ti) {
    acc[ti][0] = (f32x4){0.f, 0.f, 0.f, 0.f};
    acc[ti][1] = (f32x4){0.f, 0.f, 0.f, 0.f};
  }

  const float* __restrict__ xb0 = x + (size_t)b * (C_N * HW_N) + (size_t)c0 * HW_N;
  const int p0 = t & 15;           // c-pair 0..15
  const int q0 = t >> 4;           // hw-quad 0..15 (then +16, +32, tail 48)

  float4 fa0, fb0, fa1, fb1, fa2, fb2, fa3, fb3;
  auto LD = [&](int ss) {
    const float* xs = xb0 + (size_t)ss * 32 * HW_N;
    const float* r0 = xs + (2 * p0) * HW_N + 4 * q0;
    fa0 = *(const float4*)r0;
    fb0 = *(const float4*)(r0 + HW_N);
    fa1 = *(const float4*)(r0 + 64);
    fb1 = *(const float4*)(r0 + 64 + HW_N);
    fa2 = *(const float4*)(r0 + 128);
    fb2 = *(const float4*)(r0 + 128 + HW_N);
    if (t < 16) {                               // tail: q=48, hw 192..195
      const float* r3 = xs + (2 * t) * HW_N + 192;
      fa3 = *(const float4*)r3;
      fb3 = *(const float4*)(r3 + HW_N);
    }
  };
  auto STORE = [&](unsigned* xw) {
    unsigned* d0 = xw + q0 * 80 + p0;          // rows 4q0..4q0+3, col-pair p0
    d0[0]  = packbf2(fa0.x, fb0.x);
    d0[20] = packbf2(fa0.y, fb0.y);
    d0[40] = packbf2(fa0.z, fb0.z);
    d0[60] = packbf2(fa0.w, fb0.w);
    unsigned* d1 = d0 + 1280;                   // rows +64
    d1[0]  = packbf2(fa1.x, fb1.x);
    d1[20] = packbf2(fa1.y, fb1.y);
    d1[40] = packbf2(fa1.z, fb1.z);
    d1[60] = packbf2(fa1.w, fb1.w);
    unsigned* d2 = d0 + 2560;                   // rows +128
    d2[0]  = packbf2(fa2.x, fb2.x);
    d2[20] = packbf2(fa2.y, fb2.y);
    d2[40] = packbf2(fa2.z, fb2.z);
    d2[60] = packbf2(fa2.w, fb2.w);
    if (t < 16) {                               // rows 192..195
      unsigned* d3 = xw + 48 * 80 + t;
      d3[0]  = packbf2(fa3.x, fb3.x);
      d3[20] = packbf2(fa3.y, fb3.y);
      d3[40] = packbf2(fa3.z, fb3.z);
      d3[60] = packbf2(fa3.w, fb3.w);
    }
  };

  LD(0);
  STORE(xTw0);
  __syncthreads();

  const bf16x8 bzero = {0, 0, 0, 0, 0, 0, 0, 0};
  for (int ss = 0; ss < 4; ++ss) {
    if (ss < 3) LD(ss + 1);          // in flight during this stage's MFMAs
    const char* xb = (const char*)xT[ss & 1];
    const int kb = ss * 64 + lq * 16;   // byte offset into waT row
    bf16x8 af0 = *(const bf16x8*)((const char*)waT + ln * 272 + kb);
    bf16x8 af1 = *(const bf16x8*)((const char*)waT + (16 + ln) * 272 + kb);
#pragma unroll
    for (int ti = 0; ti < 4; ++ti) {
      int ht = w + ti * 4;
      if (ht < 13) {
        int hwrow = ht * 16 + ln;
        int rr = hwrow < HW_N ? hwrow : 0;      // clamp; masked below
        bf16x8 v = *(const bf16x8*)(xb + rr * 80 + lq * 16);
        bf16x8 bfr = (hwrow < HW_N) ? v : bzero;
        acc[ti][0] = __builtin_amdgcn_mfma_f32_16x16x32_bf16(af0, bfr, acc[ti][0], 0, 0, 0);
        acc[ti][1] = __builtin_amdgcn_mfma_f32_16x16x32_bf16(af1, bfr, acc[ti][1], 0, 0, 0);
      }
    }
    if (ss < 3) STORE((ss & 1) ? xTw0 : xTw1);  // write OTHER buffer
    __syncthreads();
  }

  // ---- store fp32 partials: z[cx][b][m][hw], hw stride 196 ----
  float* zc = z + (size_t)(cx * B_N + b) * (M_N * HW_N);
#pragma unroll
  for (int ti = 0; ti < 4; ++ti) {
    int ht = w + ti * 4;
    if (ht < 13) {
      int hw = ht * 16 + ln;
      if (hw < HW_N) {
#pragma unroll
        for (int mt = 0; mt < 2; ++mt) {
#pragma unroll
          for (int r = 0; r < 4; ++r) {
            int m = mt * 16 + lq * 4 + r;      // C-layout: row = quad*4 + reg
            zc[(size_t)m * HW_N + hw] = acc[ti][mt][r];
          }
        }
      }
    }
  }
}

// ---------------------------------------------------------------------------
// K1b: Apad[b][m][hwp] = sigmoid(ba[m] + sum_cx z[cx][b][m][hw]), 0 for pad.
// grid(1792), block 256 — pure streaming reduce (26.6MB, ~5us).
// ---------------------------------------------------------------------------
__global__ __launch_bounds__(256) void k1b_sig(
    const float* __restrict__ z, const float* __restrict__ ba,
    short* __restrict__ Apad) {
  int idx = blockIdx.x * 256 + threadIdx.x;      // 64*32*224 = 458752
  int b = idx / (M_N * HWP);
  int r = idx - b * (M_N * HWP);
  int m = r / HWP;
  int hw = r - m * HWP;
  short out = 0;
  if (hw < HW_N) {
    float s = ba[m];
    size_t base = ((size_t)b * M_N + m) * HW_N + hw;
#pragma unroll
    for (int cx = 0; cx < NCH; ++cx)
      s += z[(size_t)cx * ZSTRIDE + base];
    out = f2bf(1.f / (1.f + __expf(-s)));
  }
  Apad[idx] = out;
}

// ---------------------------------------------------------------------------
// K2: BAP -> featsb in MFMA-fragment layout:
//   offset(b,m,c) = (sg*4+bt)*512 + lq2*128 + bl*8 + j  (shorts)
//   sg=m*64+(c>>5), bt=b>>4, bl=b&15, lq2=(c>>3)&3, j=c&7.
// grid(32,16), block 256: each block owns 64 c x 4 consecutive b. The four
// b-streams are INTERLEAVED per k-step (8 float4 in flight/lane) with a
// 1-deep x prefetch, instead of 4 serial passes — latency hides under the
// 8 MFMAs + cvts of each step. Coalesced 64B-line epilogue via LDS.
// ---------------------------------------------------------------------------
__global__ __launch_bounds__(256) void k2_bap(
    const float* __restrict__ x, const short* __restrict__ Apad,
    short* __restrict__ featsb) {
  __shared__ short tb[8192];   // [m][och][lq2][bi][j] = m*256+och*128+lq2*32+bi*8+j
  const int t = threadIdx.x;
  const int w = t >> 6, lane = t & 63, lq = lane >> 4, ln = lane & 15;
  const int cx = blockIdx.x;           // c-tile 0..31
  const int bq = blockIdx.y;           // b-quad 0..15
  const int cl = w * 16 + ln;          // c within tile 0..63
  const int c = cx * 64 + cl;
  const float sc = 1.f / (float)HW_N;
  const int och = cl >> 5, lq2w = (cl >> 3) & 3, j = cl & 7;
  const size_t bstr = (size_t)C_N * HW_N;
  const float* __restrict__ xrow0 = x + (size_t)(bq * 4) * bstr + (size_t)c * HW_N;

  const short* apb[4];
#pragma unroll
  for (int bi = 0; bi < 4; ++bi)
    apb[bi] = Apad + ((size_t)(bq * 4 + bi) * M_N + ln) * HWP + lq * 8;

  f32x4 d0[4], d1[4];
#pragma unroll
  for (int bi = 0; bi < 4; ++bi) {
    d0[bi] = (f32x4){0.f, 0.f, 0.f, 0.f};
    d1[bi] = (f32x4){0.f, 0.f, 0.f, 0.f};
  }

  float4 xa[4], xc[4];
#pragma unroll
  for (int bi = 0; bi < 4; ++bi) {     // prologue: step 0 loads
    const float* p = xrow0 + bi * bstr + lq * 8;
    xa[bi] = *(const float4*)p;
    xc[bi] = *(const float4*)(p + 4);
  }

#pragma unroll
  for (int s = 0; s < 7; ++s) {
    float4 na[4], nc[4];
    if (s < 6) {                       // prefetch step s+1 before MFMAs of s
      if (s + 1 < 6) {
        const int h = (s + 1) * 32 + lq * 8;
#pragma unroll
        for (int bi = 0; bi < 4; ++bi) {
          const float* p = xrow0 + bi * bstr + h;
          na[bi] = *(const float4*)p;
          nc[bi] = *(const float4*)(p + 4);
        }
      } else {
        // tail step: hw 192..223 — only lq==0 j0..3 (hw 192..195) exists
#pragma unroll
        for (int bi = 0; bi < 4; ++bi) {
          float4 z4 = make_float4(0.f, 0.f, 0.f, 0.f);
          na[bi] = z4; nc[bi] = z4;
          if (lq == 0) na[bi] = *(const float4*)(xrow0 + bi * bstr + 192);
        }
      }
    }
#pragma unroll
    for (int bi = 0; bi < 4; ++bi) {
      bf16x8 a0 = *(const bf16x8*)(apb[bi] + s * 32);
      bf16x8 a1 = *(const bf16x8*)(apb[bi] + 16 * HWP + s * 32);
      bf16x8 bfr;
      bfr[0]=f2bf(xa[bi].x); bfr[1]=f2bf(xa[bi].y); bfr[2]=f2bf(xa[bi].z); bfr[3]=f2bf(xa[bi].w);
      bfr[4]=f2bf(xc[bi].x); bfr[5]=f2bf(xc[bi].y); bfr[6]=f2bf(xc[bi].z); bfr[7]=f2bf(xc[bi].w);
      d0[bi] = __builtin_amdgcn_mfma_f32_16x16x32_bf16(a0, bfr, d0[bi], 0, 0, 0);
      d1[bi] = __builtin_amdgcn_mfma_f32_16x16x32_bf16(a1, bfr, d1[bi], 0, 0, 0);
    }
    if (s < 6) {
#pragma unroll
      for (int bi = 0; bi < 4; ++bi) { xa[bi] = na[bi]; xc[bi] = nc[bi]; }
    }
  }

  // deposit into transpose tile (C-layout: row m = quad*4 + reg, col = ln)
#pragma unroll
  for (int bi = 0; bi < 4; ++bi) {
#pragma unroll
    for (int r = 0; r < 4; ++r) {
      int m0 = lq * 4 + r;
      tb[m0 * 256 + och * 128 + lq2w * 32 + bi * 8 + j]        = f2bf(d0[bi][r] * sc);
      tb[(16 + m0) * 256 + och * 128 + lq2w * 32 + bi * 8 + j] = f2bf(d1[bi][r] * sc);
    }
  }
  __syncthreads();

  // epilogue: thread t owns 32 consecutive shorts (m, och, lq2) x (bi,j)
  const int me = t >> 3, oche = (t >> 2) & 1, lq2e = t & 3;
  const short* srcp = tb + t * 32;
  uint4 v0 = *(const uint4*)(srcp);
  uint4 v1 = *(const uint4*)(srcp + 8);
  uint4 v2 = *(const uint4*)(srcp + 16);
  uint4 v3 = *(const uint4*)(srcp + 24);
  const int sg = me * 64 + cx * 2 + oche;
  const int bt = bq >> 2;
  short* dst = featsb + (size_t)(sg * 4 + bt) * 512 + lq2e * 128 + (bq & 3) * 32;
  *(uint4*)(dst)      = v0;
  *(uint4*)(dst + 8)  = v1;
  *(uint4*)(dst + 16) = v2;
  *(uint4*)(dst + 24) = v3;
}

// ---------------------------------------------------------------------------
// K3: partial[kc][b][n] = sum_{k in chunk} feats[b][k] * Wc[n][k]
// grid(7,128), block 256, k-chunk 512 (16 steps) -> 896 blocks = 3.5
// waves/SIMD. 2-deep rotating prefetch (3 register slots, fully unrolled so
// all slot indices are compile-time) keeps ~18 loads/wave in flight.
// A-frags: coalesced 1KB wave loads from fragment-layout featsb.
// B-frags: direct Wc float4 pairs (16 rows x 64B contiguous segments).
// ---------------------------------------------------------------------------
__global__ __launch_bounds__(256) void k3_cls(
    const short* __restrict__ featsb, const float* __restrict__ Wc,
    float* __restrict__ partial) {
  const int t = threadIdx.x;
  const int w = t >> 6, lane = t & 63, lq = lane >> 4, ln = lane & 15;
  const int n = blockIdx.x * 64 + w * 16 + ln;
  const int nc = n < NC_N ? n : NC_N - 1;
  const int kc = blockIdx.y;
  const float* __restrict__ wrow = Wc + (size_t)nc * K_N + (size_t)kc * 512 + lq * 8;
  const short* __restrict__ fb = featsb + (size_t)(kc * 16) * 2048 + lane * 8;

  f32x4 acc0 = {0.f,0.f,0.f,0.f}, acc1 = {0.f,0.f,0.f,0.f};
  f32x4 acc2 = {0.f,0.f,0.f,0.f}, acc3 = {0.f,0.f,0.f,0.f};

  float4 pw0[3], pw1[3];
  bf16x8 pa0[3], pa1[3], pa2[3], pa3[3];
#define K3LD(S, SL) do {                                           \
    const float* wn_ = wrow + (S) * 32;                            \
    pw0[SL] = *(const float4*)wn_;                                 \
    pw1[SL] = *(const float4*)(wn_ + 4);                           \
    const short* fs_ = fb + (size_t)(S) * 2048;                    \
    pa0[SL] = *(const bf16x8*)(fs_);                               \
    pa1[SL] = *(const bf16x8*)(fs_ + 512);                         \
    pa2[SL] = *(const bf16x8*)(fs_ + 1024);                        \
    pa3[SL] = *(const bf16x8*)(fs_ + 1536);                        \
  } while (0)

  K3LD(0, 0);
  K3LD(1, 1);
#pragma unroll
  for (int s = 0; s < 16; ++s) {
    if (s + 2 < 16) K3LD(s + 2, (s + 2) % 3);
    const int sl = s % 3;
    bf16x8 bfr;
    bfr[0]=f2bf(pw0[sl].x); bfr[1]=f2bf(pw0[sl].y); bfr[2]=f2bf(pw0[sl].z); bfr[3]=f2bf(pw0[sl].w);
    bfr[4]=f2bf(pw1[sl].x); bfr[5]=f2bf(pw1[sl].y); bfr[6]=f2bf(pw1[sl].z); bfr[7]=f2bf(pw1[sl].w);
    acc0 = __builtin_amdgcn_mfma_f32_16x16x32_bf16(pa0[sl], bfr, acc0, 0, 0, 0);
    acc1 = __builtin_amdgcn_mfma_f32_16x16x32_bf16(pa1[sl], bfr, acc1, 0, 0, 0);
    acc2 = __builtin_amdgcn_mfma_f32_16x16x32_bf16(pa2[sl], bfr, acc2, 0, 0, 0);
    acc3 = __builtin_amdgcn_mfma_f32_16x16x32_bf16(pa3[sl], bfr, acc3, 0, 0, 0);
  }
#undef K3LD

  if (n < NC_N) {
    float* po = partial + (size_t)kc * (B_N * NC_N) + n;
#pragma unroll
    for (int r = 0; r < 4; ++r) {
      int br = lq * 4 + r;                    // b within 16-tile
      po[(size_t)br * NC_N]        = acc0[r];
      po[(size_t)(16 + br) * NC_N] = acc1[r];
      po[(size_t)(32 + br) * NC_N] = acc2[r];
      po[(size_t)(48 + br) * NC_N] = acc3[r];
    }
  }
}

// ---------------------------------------------------------------------------
// K4: out[b][n] = bc[n] + sum_kc partial[kc][b][n]   (128 chunks)
// ---------------------------------------------------------------------------
__global__ __launch_bounds__(256) void k4_reduce(
    const float* __restrict__ partial, const float* __restrict__ bc,
    float* __restrict__ out) {
  int idx = blockIdx.x * 256 + threadIdx.x;  // 25344 total
  if (idx >= B_N * NC_N) return;
  int n = idx % NC_N;
  float s = bc[n];
#pragma unroll 8
  for (int kc = 0; kc < KCH; ++kc) s += partial[(size_t)kc * (B_N * NC_N) + idx];
  out[idx] = s;
}

// ---------------------------------------------------------------------------
extern "C" void kernel_launch(void* const* d_in, const int* in_sizes, int n_in,
                              void* d_out, int out_size, void* d_ws, size_t ws_size,
                              hipStream_t stream) {
  const float* x  = (const float*)d_in[0];
  const float* Wa = (const float*)d_in[1];
  const float* ba = (const float*)d_in[2];
  const float* Wc = (const float*)d_in[3];
  const float* bc = (const float*)d_in[4];
  float* out = (float*)d_out;

  char* wsb = (char*)d_ws;
  short* Apad    = (short*)(wsb);                // 64*32*224*2    = 0.92 MB
  short* featsb  = (short*)(wsb + (1u  << 20));  // 2048*2048*2    = 8.39 MB (frag layout)
  float* zbuf    = (float*)(wsb + (10u << 20));  // 16*401408*4    = 25.69 MB
  float* partial = (float*)(wsb + (40u << 20));  // 128*25344*4    = 12.98 MB
  (void)ws_size; (void)in_sizes; (void)n_in; (void)out_size;

  hipLaunchKernelGGL(k1a_partial, dim3(NCH, B_N), dim3(256), 0, stream,
                     x, Wa, zbuf);
  hipLaunchKernelGGL(k1b_sig, dim3(1792), dim3(256), 0, stream,
                     zbuf, ba, Apad);
  hipLaunchKernelGGL(k2_bap, dim3(32, 16), dim3(256), 0, stream,
                     x, Apad, featsb);
  hipLaunchKernelGGL(k3_cls, dim3(7, KCH), dim3(256), 0, stream,
                     featsb, Wc, partial);
  hipLaunchKernelGGL(k4_reduce, dim3(99), dim3(256), 0, stream,
                     partial, bc, out);
}

// Round 7
// 280.106 us; speedup vs baseline: 1.0100x; 1.0100x over previous
//
#include <hip/hip_runtime.h>
#include <hip/hip_bf16.h>
#include <cstdint>

#define B_N 64
#define C_N 2048
#define HW_N 196
#define HWP 224          // zero-padded hw length for A (7 k-steps of 32)
#define M_N 32
#define NC_N 396
#define K_N 65536        // M_N * C_N
#define CCH 256          // c-chunk per k1a block
#define NCH 8            // number of c-chunks
#define KCH 128          // k3 k-chunks (k-chunk = 512)
#define ZSTRIDE (B_N * M_N * HW_N)   // 401408 floats per chunk-partial

typedef __attribute__((ext_vector_type(8))) short bf16x8;
typedef __attribute__((ext_vector_type(4))) float f32x4;

__device__ inline short f2bf(float x) {   // RNE fp32 -> bf16
  union { float f; unsigned u; } v; v.f = x;
  unsigned r = (v.u + 0x7FFFu + ((v.u >> 16) & 1u)) >> 16;
  return (short)r;
}

__device__ inline unsigned packbf2(float lo, float hi) {  // lo -> low 16 bits
  return ((unsigned)(unsigned short)f2bf(hi) << 16) |
         (unsigned)(unsigned short)f2bf(lo);
}

// ---------------------------------------------------------------------------
// K1a: z[cx][b][m][hw] = sum_{c in chunk cx} x[b][c][hw] * Wa[m][c]
// grid(8,64), block 256 (4 waves). DOUBLE-BUFFERED xT stage: stage ss+1's
// global loads are issued into registers BEFORE stage ss's MFMAs, the
// pack+ds_write lands in the other buffer after them, one barrier per stage.
// (r5-verified version, unchanged.)
// ---------------------------------------------------------------------------
__global__ __launch_bounds__(256) void k1a_partial(
    const float* __restrict__ x, const float* __restrict__ Wa,
    float* __restrict__ z) {
  __shared__ short waT[32][264];      // Wa chunk bf16, row stride 528B (pad +8)
  __shared__ short xT[2][208][40];    // x^T stages [hw][c'] bf16, stride 80B
  const int t = threadIdx.x;
  const int w = t >> 6, lane = t & 63, lq = lane >> 4, ln = lane & 15;
  const int cx = blockIdx.x, b = blockIdx.y;
  const int c0 = cx * CCH;

  unsigned* xTw0 = (unsigned*)xT[0];
  unsigned* xTw1 = (unsigned*)xT[1];
  // zero hw rows 196..207 of both buffers (read by tile 12, masked on store)
  if (t < 240) { xTw0[196 * 20 + t] = 0u; xTw1[196 * 20 + t] = 0u; }
  // stage Wa[0:32][c0:c0+256] -> waT (bf16), coalesced row-major reads
  for (int i = t; i < 2048; i += 256) {
    int m = i >> 6, f4 = i & 63;
    float4 v = *(const float4*)(Wa + (size_t)m * C_N + c0 + f4 * 4);
    uint2 pk;
    pk.x = packbf2(v.x, v.y);
    pk.y = packbf2(v.z, v.w);
    *(uint2*)((char*)waT + m * 528 + f4 * 8) = pk;
  }

  f32x4 acc[4][2];
#pragma unroll
  for (int ti = 0; ti < 4; ++ti) {
    acc[ti][0] = (f32x4){0.f, 0.f, 0.f, 0.f};
    acc[ti][1] = (f32x4){0.f, 0.f, 0.f, 0.f};
  }

  const float* __restrict__ xb0 = x + (size_t)b * (C_N * HW_N) + (size_t)c0 * HW_N;
  const int p0 = t & 15;           // c-pair 0..15
  const int q0 = t >> 4;           // hw-quad 0..15 (then +16, +32, tail 48)

  float4 fa0, fb0, fa1, fb1, fa2, fb2, fa3, fb3;
  auto LD = [&](int ss) {
    const float* xs = xb0 + (size_t)ss * 32 * HW_N;
    const float* r0 = xs + (2 * p0) * HW_N + 4 * q0;
    fa0 = *(const float4*)r0;
    fb0 = *(const float4*)(r0 + HW_N);
    fa1 = *(const float4*)(r0 + 64);
    fb1 = *(const float4*)(r0 + 64 + HW_N);
    fa2 = *(const float4*)(r0 + 128);
    fb2 = *(const float4*)(r0 + 128 + HW_N);
    if (t < 16) {                               // tail: q=48, hw 192..195
      const float* r3 = xs + (2 * t) * HW_N + 192;
      fa3 = *(const float4*)r3;
      fb3 = *(const float4*)(r3 + HW_N);
    }
  };
  auto STORE = [&](unsigned* xw) {
    unsigned* d0 = xw + q0 * 80 + p0;          // row 4*q0, col-pair p0
    d0[0]  = packbf2(fa0.x, fb0.x);
    d0[20] = packbf2(fa0.y, fb0.y);
    d0[40] = packbf2(fa0.z, fb0.z);
    d0[60] = packbf2(fa0.w, fb0.w);
    unsigned* d1 = d0 + 1280;                   // q0+16
    d1[0]  = packbf2(fa1.x, fb1.x);
    d1[20] = packbf2(fa1.y, fb1.y);
    d1[40] = packbf2(fa1.z, fb1.z);
    d1[60] = packbf2(fa1.w, fb1.w);
    unsigned* d2 = d0 + 2560;                   // q0+32
    d2[0]  = packbf2(fa2.x, fb2.x);
    d2[20] = packbf2(fa2.y, fb2.y);
    d2[40] = packbf2(fa2.z, fb2.z);
    d2[60] = packbf2(fa2.w, fb2.w);
    if (t < 16) {
      unsigned* d3 = xw + 48 * 80 + t;
      d3[0]  = packbf2(fa3.x, fb3.x);
      d3[20] = packbf2(fa3.y, fb3.y);
      d3[40] = packbf2(fa3.z, fb3.z);
      d3[60] = packbf2(fa3.w, fb3.w);
    }
  };

  LD(0);
  STORE(xTw0);
  __syncthreads();

  for (int ss = 0; ss < 8; ++ss) {
    if (ss < 7) LD(ss + 1);          // in flight during this stage's MFMAs
    const char* xb = (const char*)xT[ss & 1];
    const int kb = ss * 64 + lq * 16;   // byte offset into waT row
    bf16x8 af0 = *(const bf16x8*)((const char*)waT + ln * 528 + kb);
    bf16x8 af1 = *(const bf16x8*)((const char*)waT + (16 + ln) * 528 + kb);
#pragma unroll
    for (int ti = 0; ti < 4; ++ti) {
      int ht = w + ti * 4;
      if (ht < 13) {
        bf16x8 bfr = *(const bf16x8*)(xb + (ht * 16 + ln) * 80 + lq * 16);
        acc[ti][0] = __builtin_amdgcn_mfma_f32_16x16x32_bf16(af0, bfr, acc[ti][0], 0, 0, 0);
        acc[ti][1] = __builtin_amdgcn_mfma_f32_16x16x32_bf16(af1, bfr, acc[ti][1], 0, 0, 0);
      }
    }
    if (ss < 7) STORE((ss & 1) ? xTw0 : xTw1);  // write OTHER buffer
    __syncthreads();
  }

  // ---- store fp32 partials: z[cx][b][m][hw], hw stride 196 ----
  float* zc = z + (size_t)(cx * B_N + b) * (M_N * HW_N);
#pragma unroll
  for (int ti = 0; ti < 4; ++ti) {
    int ht = w + ti * 4;
    if (ht < 13) {
      int hw = ht * 16 + ln;
      if (hw < HW_N) {
#pragma unroll
        for (int mt = 0; mt < 2; ++mt) {
#pragma unroll
          for (int r = 0; r < 4; ++r) {
            int m = mt * 16 + lq * 4 + r;      // C-layout: row = quad*4 + reg
            zc[(size_t)m * HW_N + hw] = acc[ti][mt][r];
          }
        }
      }
    }
  }
}

// ---------------------------------------------------------------------------
// K1b: Apad[b][m][hwp] = sigmoid(ba[m] + sum_cx z[cx][b][m][hw]), 0 for pad.
// grid(1792), block 256 — pure streaming reduce (13.8MB, ~5us).
// ---------------------------------------------------------------------------
__global__ __launch_bounds__(256) void k1b_sig(
    const float* __restrict__ z, const float* __restrict__ ba,
    short* __restrict__ Apad) {
  int idx = blockIdx.x * 256 + threadIdx.x;      // 64*32*224 = 458752
  int b = idx / (M_N * HWP);
  int r = idx - b * (M_N * HWP);
  int m = r / HWP;
  int hw = r - m * HWP;
  short out = 0;
  if (hw < HW_N) {
    float s = ba[m];
    size_t base = ((size_t)b * M_N + m) * HW_N + hw;
#pragma unroll
    for (int cx = 0; cx < NCH; ++cx)
      s += z[(size_t)cx * ZSTRIDE + base];
    out = f2bf(1.f / (1.f + __expf(-s)));
  }
  Apad[idx] = out;
}

// ---------------------------------------------------------------------------
// K2: BAP -> featsb in MFMA-fragment layout:
//   offset(b,m,c) = (sg*4+bt)*512 + lq2*128 + bl*8 + j  (shorts)
//   sg=m*64+(c>>5), bt=b>>4, bl=b&15, lq2=(c>>3)&3, j=c&7.
// grid(32,16), block 256: each block owns 64 c x 4 consecutive b. The b's
// are processed in PAIRS of interleaved streams (2 passes of 2) with a
// 1-deep x prefetch: 8 loads in flight per step per lane at ~110 VGPR —
// double the serial version's MLP without crossing the 128-VGPR occupancy
// step (r6's 4-wide interleave did, and regressed). Coalesced 64B-line
// epilogue via LDS unchanged.
// ---------------------------------------------------------------------------
__global__ __launch_bounds__(256) void k2_bap(
    const float* __restrict__ x, const short* __restrict__ Apad,
    short* __restrict__ featsb) {
  __shared__ short tb[8192];   // [m][och][lq2][bi][j] = m*256+och*128+lq2*32+bi*8+j
  const int t = threadIdx.x;
  const int w = t >> 6, lane = t & 63, lq = lane >> 4, ln = lane & 15;
  const int cx = blockIdx.x;           // c-tile 0..31
  const int bq = blockIdx.y;           // b-quad 0..15
  const int cl = w * 16 + ln;          // c within tile 0..63
  const int c = cx * 64 + cl;
  const float sc = 1.f / (float)HW_N;
  const int och = cl >> 5, lq2w = (cl >> 3) & 3, j = cl & 7;
  const size_t bstr = (size_t)C_N * HW_N;
  const float* __restrict__ xrow0 = x + (size_t)(bq * 4) * bstr + (size_t)c * HW_N;

  f32x4 d0[4], d1[4];
#pragma unroll
  for (int bi = 0; bi < 4; ++bi) {
    d0[bi] = (f32x4){0.f, 0.f, 0.f, 0.f};
    d1[bi] = (f32x4){0.f, 0.f, 0.f, 0.f};
  }

#pragma unroll
  for (int bp = 0; bp < 2; ++bp) {
    const float* __restrict__ xrA = xrow0 + (size_t)(bp * 2) * bstr;
    const float* __restrict__ xrB = xrA + bstr;
    const short* __restrict__ apA = Apad + ((size_t)(bq * 4 + bp * 2) * M_N + ln) * HWP + lq * 8;
    const short* __restrict__ apB = apA + (size_t)M_N * HWP;

    // prologue: step 0 loads for both streams
    float4 xaA = *(const float4*)(xrA + lq * 8);
    float4 xcA = *(const float4*)(xrA + lq * 8 + 4);
    float4 xaB = *(const float4*)(xrB + lq * 8);
    float4 xcB = *(const float4*)(xrB + lq * 8 + 4);

#pragma unroll
    for (int s = 0; s < 7; ++s) {
      float4 naA, ncA, naB, ncB;
      if (s < 6) {                       // prefetch step s+1 before MFMAs of s
        if (s + 1 < 6) {
          const int h = (s + 1) * 32 + lq * 8;
          naA = *(const float4*)(xrA + h);
          ncA = *(const float4*)(xrA + h + 4);
          naB = *(const float4*)(xrB + h);
          ncB = *(const float4*)(xrB + h + 4);
        } else {
          // tail step: hw 192..223 — only lq==0 j0..3 (hw 192..195) exists
          float4 z4 = make_float4(0.f, 0.f, 0.f, 0.f);
          naA = z4; ncA = z4; naB = z4; ncB = z4;
          if (lq == 0) {
            naA = *(const float4*)(xrA + 192);
            naB = *(const float4*)(xrB + 192);
          }
        }
      }
      // stream A
      {
        bf16x8 a0 = *(const bf16x8*)(apA + s * 32);
        bf16x8 a1 = *(const bf16x8*)(apA + 16 * HWP + s * 32);
        bf16x8 bfr;
        bfr[0]=f2bf(xaA.x); bfr[1]=f2bf(xaA.y); bfr[2]=f2bf(xaA.z); bfr[3]=f2bf(xaA.w);
        bfr[4]=f2bf(xcA.x); bfr[5]=f2bf(xcA.y); bfr[6]=f2bf(xcA.z); bfr[7]=f2bf(xcA.w);
        d0[bp*2] = __builtin_amdgcn_mfma_f32_16x16x32_bf16(a0, bfr, d0[bp*2], 0, 0, 0);
        d1[bp*2] = __builtin_amdgcn_mfma_f32_16x16x32_bf16(a1, bfr, d1[bp*2], 0, 0, 0);
      }
      // stream B
      {
        bf16x8 a0 = *(const bf16x8*)(apB + s * 32);
        bf16x8 a1 = *(const bf16x8*)(apB + 16 * HWP + s * 32);
        bf16x8 bfr;
        bfr[0]=f2bf(xaB.x); bfr[1]=f2bf(xaB.y); bfr[2]=f2bf(xaB.z); bfr[3]=f2bf(xaB.w);
        bfr[4]=f2bf(xcB.x); bfr[5]=f2bf(xcB.y); bfr[6]=f2bf(xcB.z); bfr[7]=f2bf(xcB.w);
        d0[bp*2+1] = __builtin_amdgcn_mfma_f32_16x16x32_bf16(a0, bfr, d0[bp*2+1], 0, 0, 0);
        d1[bp*2+1] = __builtin_amdgcn_mfma_f32_16x16x32_bf16(a1, bfr, d1[bp*2+1], 0, 0, 0);
      }
      if (s < 6) {
        xaA = naA; xcA = ncA; xaB = naB; xcB = ncB;
      }
    }
  }

  // deposit into transpose tile (C-layout: row m = quad*4 + reg, col = ln)
#pragma unroll
  for (int bi = 0; bi < 4; ++bi) {
#pragma unroll
    for (int r = 0; r < 4; ++r) {
      int m0 = lq * 4 + r;
      tb[m0 * 256 + och * 128 + lq2w * 32 + bi * 8 + j]        = f2bf(d0[bi][r] * sc);
      tb[(16 + m0) * 256 + och * 128 + lq2w * 32 + bi * 8 + j] = f2bf(d1[bi][r] * sc);
    }
  }
  __syncthreads();

  // epilogue: thread t owns 32 consecutive shorts (m, och, lq2) x (bi,j)
  const int me = t >> 3, oche = (t >> 2) & 1, lq2e = t & 3;
  const short* srcp = tb + t * 32;
  uint4 v0 = *(const uint4*)(srcp);
  uint4 v1 = *(const uint4*)(srcp + 8);
  uint4 v2 = *(const uint4*)(srcp + 16);
  uint4 v3 = *(const uint4*)(srcp + 24);
  const int sg = me * 64 + cx * 2 + oche;
  const int bt = bq >> 2;
  short* dst = featsb + (size_t)(sg * 4 + bt) * 512 + lq2e * 128 + (bq & 3) * 32;
  *(uint4*)(dst)      = v0;
  *(uint4*)(dst + 8)  = v1;
  *(uint4*)(dst + 16) = v2;
  *(uint4*)(dst + 24) = v3;
}

// ---------------------------------------------------------------------------
// K3: partial[kc][b][n] = sum_{k in chunk} feats[b][k] * Wc[n][k]
// grid(7,128), block 256, k-chunk 512 (16 steps) -> 896 blocks = 14 waves/CU
// (the r3-verified variant). 1-deep prefetch, ~90 VGPR (below the 128 step).
// A-frags: coalesced 1KB wave loads from fragment-layout featsb.
// B-frags: direct Wc float4 pairs (16 rows x 64B contiguous segments).
// ---------------------------------------------------------------------------
__global__ __launch_bounds__(256) void k3_cls(
    const short* __restrict__ featsb, const float* __restrict__ Wc,
    float* __restrict__ partial) {
  const int t = threadIdx.x;
  const int w = t >> 6, lane = t & 63, lq = lane >> 4, ln = lane & 15;
  const int n = blockIdx.x * 64 + w * 16 + ln;
  const int nc = n < NC_N ? n : NC_N - 1;
  const int kc = blockIdx.y;
  const size_t k0 = (size_t)kc * 512;
  const float* __restrict__ wrow = Wc + (size_t)nc * K_N + k0 + lq * 8;
  // fragment base: steps sg = kc*16 + s; per-step stride 2048 shorts.
  const short* __restrict__ fb = featsb + (size_t)(kc * 16) * 2048 + lane * 8;

  f32x4 acc0 = {0.f,0.f,0.f,0.f}, acc1 = {0.f,0.f,0.f,0.f};
  f32x4 acc2 = {0.f,0.f,0.f,0.f}, acc3 = {0.f,0.f,0.f,0.f};

  float4 cw0 = *(const float4*)(wrow);
  float4 cw1 = *(const float4*)(wrow + 4);
  bf16x8 ca0 = *(const bf16x8*)(fb);
  bf16x8 ca1 = *(const bf16x8*)(fb + 512);
  bf16x8 ca2 = *(const bf16x8*)(fb + 1024);
  bf16x8 ca3 = *(const bf16x8*)(fb + 1536);

#pragma unroll
  for (int s = 0; s < 16; ++s) {
    float4 nw0, nw1; bf16x8 na0, na1, na2, na3;
    if (s < 15) {                    // prefetch step s+1 before MFMAs of s
      const float* wn = wrow + (s + 1) * 32;
      nw0 = *(const float4*)(wn);
      nw1 = *(const float4*)(wn + 4);
      const short* fs = fb + (size_t)(s + 1) * 2048;
      na0 = *(const bf16x8*)(fs);
      na1 = *(const bf16x8*)(fs + 512);
      na2 = *(const bf16x8*)(fs + 1024);
      na3 = *(const bf16x8*)(fs + 1536);
    }
    bf16x8 bfr;
    bfr[0]=f2bf(cw0.x); bfr[1]=f2bf(cw0.y); bfr[2]=f2bf(cw0.z); bfr[3]=f2bf(cw0.w);
    bfr[4]=f2bf(cw1.x); bfr[5]=f2bf(cw1.y); bfr[6]=f2bf(cw1.z); bfr[7]=f2bf(cw1.w);
    acc0 = __builtin_amdgcn_mfma_f32_16x16x32_bf16(ca0, bfr, acc0, 0, 0, 0);
    acc1 = __builtin_amdgcn_mfma_f32_16x16x32_bf16(ca1, bfr, acc1, 0, 0, 0);
    acc2 = __builtin_amdgcn_mfma_f32_16x16x32_bf16(ca2, bfr, acc2, 0, 0, 0);
    acc3 = __builtin_amdgcn_mfma_f32_16x16x32_bf16(ca3, bfr, acc3, 0, 0, 0);
    if (s < 15) {
      cw0 = nw0; cw1 = nw1;
      ca0 = na0; ca1 = na1; ca2 = na2; ca3 = na3;
    }
  }
  if (n < NC_N) {
    float* po = partial + (size_t)kc * (B_N * NC_N) + n;
#pragma unroll
    for (int r = 0; r < 4; ++r) {
      int br = lq * 4 + r;                    // b within 16-tile
      po[(size_t)br * NC_N]        = acc0[r];
      po[(size_t)(16 + br) * NC_N] = acc1[r];
      po[(size_t)(32 + br) * NC_N] = acc2[r];
      po[(size_t)(48 + br) * NC_N] = acc3[r];
    }
  }
}

// ---------------------------------------------------------------------------
// K4: out[b][n] = bc[n] + sum_kc partial[kc][b][n]   (128 chunks)
// ---------------------------------------------------------------------------
__global__ __launch_bounds__(256) void k4_reduce(
    const float* __restrict__ partial, const float* __restrict__ bc,
    float* __restrict__ out) {
  int idx = blockIdx.x * 256 + threadIdx.x;  // 25344 total
  if (idx >= B_N * NC_N) return;
  int n = idx % NC_N;
  float s = bc[n];
#pragma unroll 8
  for (int kc = 0; kc < KCH; ++kc) s += partial[(size_t)kc * (B_N * NC_N) + idx];
  out[idx] = s;
}

// ---------------------------------------------------------------------------
extern "C" void kernel_launch(void* const* d_in, const int* in_sizes, int n_in,
                              void* d_out, int out_size, void* d_ws, size_t ws_size,
                              hipStream_t stream) {
  const float* x  = (const float*)d_in[0];
  const float* Wa = (const float*)d_in[1];
  const float* ba = (const float*)d_in[2];
  const float* Wc = (const float*)d_in[3];
  const float* bc = (const float*)d_in[4];
  float* out = (float*)d_out;

  char* wsb = (char*)d_ws;
  short* Apad    = (short*)(wsb);                // 64*32*224*2    = 0.92 MB
  short* featsb  = (short*)(wsb + (1u  << 20));  // 2048*2048*2    = 8.39 MB (frag layout)
  float* zbuf    = (float*)(wsb + (10u << 20));  // 8*401408*4     = 12.85 MB
  float* partial = (float*)(wsb + (40u << 20));  // 128*25344*4    = 12.98 MB
  (void)ws_size; (void)in_sizes; (void)n_in; (void)out_size;

  hipLaunchKernelGGL(k1a_partial, dim3(NCH, B_N), dim3(256), 0, stream,
                     x, Wa, zbuf);
  hipLaunchKernelGGL(k1b_sig, dim3(1792), dim3(256), 0, stream,
                     zbuf, ba, Apad);
  hipLaunchKernelGGL(k2_bap, dim3(32, 16), dim3(256), 0, stream,
                     x, Apad, featsb);
  hipLaunchKernelGGL(k3_cls, dim3(7, KCH), dim3(256), 0, stream,
                     featsb, Wc, partial);
  hipLaunchKernelGGL(k4_reduce, dim3(99), dim3(256), 0, stream,
                     partial, bc, out);
}

// Round 9
// 277.194 us; speedup vs baseline: 1.0206x; 1.0105x over previous
//
#include <hip/hip_runtime.h>
#include <hip/hip_bf16.h>
#include <cstdint>

#define B_N 64
#define C_N 2048
#define HW_N 196
#define HWP 224          // zero-padded hw length for A (7 k-steps of 32)
#define M_N 32
#define NC_N 396
#define K_N 65536        // M_N * C_N
#define CCH 256          // c-chunk per k1a block
#define NCH 8            // number of c-chunks
#define KCH 256          // k3 k-chunks (k-chunk = 256)
#define ZSTRIDE (B_N * M_N * HW_N)   // 401408 floats per chunk-partial

typedef __attribute__((ext_vector_type(8))) short bf16x8;
typedef __attribute__((ext_vector_type(4))) float f32x4;

__device__ inline short f2bf(float x) {   // RNE fp32 -> bf16
  union { float f; unsigned u; } v; v.f = x;
  unsigned r = (v.u + 0x7FFFu + ((v.u >> 16) & 1u)) >> 16;
  return (short)r;
}

__device__ inline unsigned packbf2(float lo, float hi) {  // lo -> low 16 bits
  return ((unsigned)(unsigned short)f2bf(hi) << 16) |
         (unsigned)(unsigned short)f2bf(lo);
}

// ---------------------------------------------------------------------------
// K1a: z[cx][b][m][hw] = sum_{c in chunk cx} x[b][c][hw] * Wa[m][c]
// grid(8,64), block 256 (4 waves). DOUBLE-BUFFERED xT stage (r5-verified,
// unchanged this round).
// ---------------------------------------------------------------------------
__global__ __launch_bounds__(256) void k1a_partial(
    const float* __restrict__ x, const float* __restrict__ Wa,
    float* __restrict__ z) {
  __shared__ short waT[32][264];      // Wa chunk bf16, row stride 528B (pad +8)
  __shared__ short xT[2][208][40];    // x^T stages [hw][c'] bf16, stride 80B
  const int t = threadIdx.x;
  const int w = t >> 6, lane = t & 63, lq = lane >> 4, ln = lane & 15;
  const int cx = blockIdx.x, b = blockIdx.y;
  const int c0 = cx * CCH;

  unsigned* xTw0 = (unsigned*)xT[0];
  unsigned* xTw1 = (unsigned*)xT[1];
  // zero hw rows 196..207 of both buffers (read by tile 12, masked on store)
  if (t < 240) { xTw0[196 * 20 + t] = 0u; xTw1[196 * 20 + t] = 0u; }
  // stage Wa[0:32][c0:c0+256] -> waT (bf16), coalesced row-major reads
  for (int i = t; i < 2048; i += 256) {
    int m = i >> 6, f4 = i & 63;
    float4 v = *(const float4*)(Wa + (size_t)m * C_N + c0 + f4 * 4);
    uint2 pk;
    pk.x = packbf2(v.x, v.y);
    pk.y = packbf2(v.z, v.w);
    *(uint2*)((char*)waT + m * 528 + f4 * 8) = pk;
  }

  f32x4 acc[4][2];
#pragma unroll
  for (int ti = 0; ti < 4; ++ti) {
    acc[ti][0] = (f32x4){0.f, 0.f, 0.f, 0.f};
    acc[ti][1] = (f32x4){0.f, 0.f, 0.f, 0.f};
  }

  const float* __restrict__ xb0 = x + (size_t)b * (C_N * HW_N) + (size_t)c0 * HW_N;
  const int p0 = t & 15;           // c-pair 0..15
  const int q0 = t >> 4;           // hw-quad 0..15 (then +16, +32, tail 48)

  float4 fa0, fb0, fa1, fb1, fa2, fb2, fa3, fb3;
  auto LD = [&](int ss) {
    const float* xs = xb0 + (size_t)ss * 32 * HW_N;
    const float* r0 = xs + (2 * p0) * HW_N + 4 * q0;
    fa0 = *(const float4*)r0;
    fb0 = *(const float4*)(r0 + HW_N);
    fa1 = *(const float4*)(r0 + 64);
    fb1 = *(const float4*)(r0 + 64 + HW_N);
    fa2 = *(const float4*)(r0 + 128);
    fb2 = *(const float4*)(r0 + 128 + HW_N);
    if (t < 16) {                               // tail: q=48, hw 192..195
      const float* r3 = xs + (2 * t) * HW_N + 192;
      fa3 = *(const float4*)r3;
      fb3 = *(const float4*)(r3 + HW_N);
    }
  };
  auto STORE = [&](unsigned* xw) {
    unsigned* d0 = xw + q0 * 80 + p0;          // row 4*q0, col-pair p0
    d0[0]  = packbf2(fa0.x, fb0.x);
    d0[20] = packbf2(fa0.y, fb0.y);
    d0[40] = packbf2(fa0.z, fb0.z);
    d0[60] = packbf2(fa0.w, fb0.w);
    unsigned* d1 = d0 + 1280;                   // q0+16
    d1[0]  = packbf2(fa1.x, fb1.x);
    d1[20] = packbf2(fa1.y, fb1.y);
    d1[40] = packbf2(fa1.z, fb1.z);
    d1[60] = packbf2(fa1.w, fb1.w);
    unsigned* d2 = d0 + 2560;                   // q0+32
    d2[0]  = packbf2(fa2.x, fb2.x);
    d2[20] = packbf2(fa2.y, fb2.y);
    d2[40] = packbf2(fa2.z, fb2.z);
    d2[60] = packbf2(fa2.w, fb2.w);
    if (t < 16) {
      unsigned* d3 = xw + 48 * 80 + t;
      d3[0]  = packbf2(fa3.x, fb3.x);
      d3[20] = packbf2(fa3.y, fb3.y);
      d3[40] = packbf2(fa3.z, fb3.z);
      d3[60] = packbf2(fa3.w, fb3.w);
    }
  };

  LD(0);
  STORE(xTw0);
  __syncthreads();

  for (int ss = 0; ss < 8; ++ss) {
    if (ss < 7) LD(ss + 1);          // in flight during this stage's MFMAs
    const char* xb = (const char*)xT[ss & 1];
    const int kb = ss * 64 + lq * 16;   // byte offset into waT row
    bf16x8 af0 = *(const bf16x8*)((const char*)waT + ln * 528 + kb);
    bf16x8 af1 = *(const bf16x8*)((const char*)waT + (16 + ln) * 528 + kb);
#pragma unroll
    for (int ti = 0; ti < 4; ++ti) {
      int ht = w + ti * 4;
      if (ht < 13) {
        bf16x8 bfr = *(const bf16x8*)(xb + (ht * 16 + ln) * 80 + lq * 16);
        acc[ti][0] = __builtin_amdgcn_mfma_f32_16x16x32_bf16(af0, bfr, acc[ti][0], 0, 0, 0);
        acc[ti][1] = __builtin_amdgcn_mfma_f32_16x16x32_bf16(af1, bfr, acc[ti][1], 0, 0, 0);
      }
    }
    if (ss < 7) STORE((ss & 1) ? xTw0 : xTw1);  // write OTHER buffer
    __syncthreads();
  }

  // ---- store fp32 partials: z[cx][b][m][hw], hw stride 196 ----
  float* zc = z + (size_t)(cx * B_N + b) * (M_N * HW_N);
#pragma unroll
  for (int ti = 0; ti < 4; ++ti) {
    int ht = w + ti * 4;
    if (ht < 13) {
      int hw = ht * 16 + ln;
      if (hw < HW_N) {
#pragma unroll
        for (int mt = 0; mt < 2; ++mt) {
#pragma unroll
          for (int r = 0; r < 4; ++r) {
            int m = mt * 16 + lq * 4 + r;      // C-layout: row = quad*4 + reg
            zc[(size_t)m * HW_N + hw] = acc[ti][mt][r];
          }
        }
      }
    }
  }
}

// ---------------------------------------------------------------------------
// K1b: Apad[b][m][hwp] = sigmoid(ba[m] + sum_cx z[cx][b][m][hw]), 0 for pad.
// grid(1792), block 256 — pure streaming reduce (13.8MB, ~5us).
// ---------------------------------------------------------------------------
__global__ __launch_bounds__(256) void k1b_sig(
    const float* __restrict__ z, const float* __restrict__ ba,
    short* __restrict__ Apad) {
  int idx = blockIdx.x * 256 + threadIdx.x;      // 64*32*224 = 458752
  int b = idx / (M_N * HWP);
  int r = idx - b * (M_N * HWP);
  int m = r / HWP;
  int hw = r - m * HWP;
  short out = 0;
  if (hw < HW_N) {
    float s = ba[m];
    size_t base = ((size_t)b * M_N + m) * HW_N + hw;
#pragma unroll
    for (int cx = 0; cx < NCH; ++cx)
      s += z[(size_t)cx * ZSTRIDE + base];
    out = f2bf(1.f / (1.f + __expf(-s)));
  }
  Apad[idx] = out;
}

// ---------------------------------------------------------------------------
// K2: BAP -> featsb in MFMA-fragment layout:
//   offset(b,m,c) = (sg*4+bt)*512 + lq2*128 + bl*8 + j  (shorts)
//   sg=m*64+(c>>5), bt=b>>4, bl=b&15, lq2=(c>>3)&3, j=c&7.
// grid(32,32), block 256: each block owns 64 c x 2 consecutive b ->
// 1024 blocks = 4 blocks/CU = 16 waves/CU (was 8 at 2 blocks/CU). Serial
// per-b MFMA loop (r5-verified structure). Epilogue: thread t owns 16
// consecutive shorts -> two uint4 stores (32B granularity; 2x featsb write
// amp = +1.3us, bought back by the occupancy doubling).
// ---------------------------------------------------------------------------
__global__ __launch_bounds__(256) void k2_bap(
    const float* __restrict__ x, const short* __restrict__ Apad,
    short* __restrict__ featsb) {
  __shared__ short tb[4096];   // [(m*2+och)*4+lq2][bi*8+j]
  const int t = threadIdx.x;
  const int w = t >> 6, lane = t & 63, lq = lane >> 4, ln = lane & 15;
  const int cx = blockIdx.x;           // c-tile 0..31 (64 c each)
  const int bq2 = blockIdx.y;          // b-pair 0..31
  const int cl = w * 16 + ln;          // c within tile 0..63
  const int c = cx * 64 + cl;
  const float sc = 1.f / (float)HW_N;
  const int och = cl >> 5, lq2w = (cl >> 3) & 3, j = cl & 7;
  const size_t bstr = (size_t)C_N * HW_N;

#pragma unroll
  for (int bi = 0; bi < 2; ++bi) {
    const int b = bq2 * 2 + bi;
    const float* __restrict__ xrow = x + (size_t)b * bstr + (size_t)c * HW_N;
    const short* __restrict__ ap0 = Apad + ((size_t)b * M_N + ln) * HWP + lq * 8;
    const short* __restrict__ ap1 = ap0 + 16 * HWP;

    f32x4 d0 = {0.f, 0.f, 0.f, 0.f}, d1 = {0.f, 0.f, 0.f, 0.f};
#pragma unroll
    for (int s = 0; s < 7; ++s) {
      bf16x8 a0 = *(const bf16x8*)(ap0 + s * 32);
      bf16x8 a1 = *(const bf16x8*)(ap1 + s * 32);
      bf16x8 bfr;
      const int h = s * 32 + lq * 8;
      if (s < 6) {
        float4 b0 = *(const float4*)(xrow + h);
        float4 b1 = *(const float4*)(xrow + h + 4);
        bfr[0]=f2bf(b0.x); bfr[1]=f2bf(b0.y); bfr[2]=f2bf(b0.z); bfr[3]=f2bf(b0.w);
        bfr[4]=f2bf(b1.x); bfr[5]=f2bf(b1.y); bfr[6]=f2bf(b1.z); bfr[7]=f2bf(b1.w);
      } else {
        // hw 192..223: only quad 0 j0..3 (hw 192..195) exists; rest hit A=0 pad
        float4 b0 = make_float4(0.f, 0.f, 0.f, 0.f);
        if (lq == 0) b0 = *(const float4*)(xrow + h);
        bfr[0]=f2bf(b0.x); bfr[1]=f2bf(b0.y); bfr[2]=f2bf(b0.z); bfr[3]=f2bf(b0.w);
        bfr[4]=0; bfr[5]=0; bfr[6]=0; bfr[7]=0;
      }
      d0 = __builtin_amdgcn_mfma_f32_16x16x32_bf16(a0, bfr, d0, 0, 0, 0);
      d1 = __builtin_amdgcn_mfma_f32_16x16x32_bf16(a1, bfr, d1, 0, 0, 0);
    }
    // deposit into transpose tile (C-layout: row m = quad*4 + reg, col = ln)
#pragma unroll
    for (int r = 0; r < 4; ++r) {
      int m0 = lq * 4 + r;
      tb[((m0 * 2 + och) * 4 + lq2w) * 16 + bi * 8 + j]        = f2bf(d0[r] * sc);
      tb[(((16 + m0) * 2 + och) * 4 + lq2w) * 16 + bi * 8 + j] = f2bf(d1[r] * sc);
    }
  }
  __syncthreads();

  // epilogue: thread t owns 16 consecutive shorts = (m, och, lq2) x (bi, j)
  const int me = t >> 3, oche = (t >> 2) & 1, lq2e = t & 3;
  const short* srcp = tb + t * 16;
  uint4 v0 = *(const uint4*)(srcp);
  uint4 v1 = *(const uint4*)(srcp + 8);
  const int sg = me * 64 + cx * 2 + oche;
  const int bt = bq2 >> 3;
  short* dst = featsb + (size_t)(sg * 4 + bt) * 512 + lq2e * 128 + (bq2 & 7) * 16;
  *(uint4*)(dst)     = v0;
  *(uint4*)(dst + 8) = v1;
}

// ---------------------------------------------------------------------------
// K3: partial[kc][b][n] = sum_{k in chunk} feats[b][k] * Wc[n][k]
// grid(7,256), block 256, k-chunk 256 (8 steps). __launch_bounds__(256,8)
// forces <=64 VGPR -> 8 waves/SIMD = 32 waves/CU resident (the m69 bucket
// boundary). NO software prefetch: TLP from 32 waves/CU replaces ILP
// (live set = 16 acc + 8 Wc + 16 feats + 4 bfr + addrs ~= 50 VGPR).
// A-frags: coalesced 1KB wave loads from fragment-layout featsb (L2-hot,
// shared by the 7 n-blocks of each kc). B-frags: direct Wc float4 pairs.
// ---------------------------------------------------------------------------
__global__ __launch_bounds__(256, 8) void k3_cls(
    const short* __restrict__ featsb, const float* __restrict__ Wc,
    float* __restrict__ partial) {
  const int t = threadIdx.x;
  const int w = t >> 6, lane = t & 63, lq = lane >> 4, ln = lane & 15;
  const int n = blockIdx.x * 64 + w * 16 + ln;
  const int nc = n < NC_N ? n : NC_N - 1;
  const int kc = blockIdx.y;           // 0..255
  const float* __restrict__ wrow = Wc + (size_t)nc * K_N + (size_t)kc * 256 + lq * 8;
  // fragment base: steps sg = kc*8 + s; per-step stride 2048 shorts.
  const short* __restrict__ fb = featsb + (size_t)(kc * 8) * 2048 + lane * 8;

  f32x4 acc0 = {0.f,0.f,0.f,0.f}, acc1 = {0.f,0.f,0.f,0.f};
  f32x4 acc2 = {0.f,0.f,0.f,0.f}, acc3 = {0.f,0.f,0.f,0.f};

#pragma unroll
  for (int s = 0; s < 8; ++s) {
    const float* wn = wrow + s * 32;
    float4 cw0 = *(const float4*)(wn);
    float4 cw1 = *(const float4*)(wn + 4);
    const short* fs = fb + (size_t)s * 2048;
    bf16x8 a0 = *(const bf16x8*)(fs);
    bf16x8 a1 = *(const bf16x8*)(fs + 512);
    bf16x8 a2 = *(const bf16x8*)(fs + 1024);
    bf16x8 a3 = *(const bf16x8*)(fs + 1536);
    bf16x8 bfr;
    bfr[0]=f2bf(cw0.x); bfr[1]=f2bf(cw0.y); bfr[2]=f2bf(cw0.z); bfr[3]=f2bf(cw0.w);
    bfr[4]=f2bf(cw1.x); bfr[5]=f2bf(cw1.y); bfr[6]=f2bf(cw1.z); bfr[7]=f2bf(cw1.w);
    acc0 = __builtin_amdgcn_mfma_f32_16x16x32_bf16(a0, bfr, acc0, 0, 0, 0);
    acc1 = __builtin_amdgcn_mfma_f32_16x16x32_bf16(a1, bfr, acc1, 0, 0, 0);
    acc2 = __builtin_amdgcn_mfma_f32_16x16x32_bf16(a2, bfr, acc2, 0, 0, 0);
    acc3 = __builtin_amdgcn_mfma_f32_16x16x32_bf16(a3, bfr, acc3, 0, 0, 0);
  }

  if (n < NC_N) {
    float* po = partial + (size_t)kc * (B_N * NC_N) + n;
#pragma unroll
    for (int r = 0; r < 4; ++r) {
      int br = lq * 4 + r;                    // b within 16-tile
      po[(size_t)br * NC_N]        = acc0[r];
      po[(size_t)(16 + br) * NC_N] = acc1[r];
      po[(size_t)(32 + br) * NC_N] = acc2[r];
      po[(size_t)(48 + br) * NC_N] = acc3[r];
    }
  }
}

// ---------------------------------------------------------------------------
// K4: out[b][n] = bc[n] + sum_kc partial[kc][b][n]   (256 chunks)
// unroll 32 -> 32KB reads in flight per wave (only 1.5 waves/CU).
// ---------------------------------------------------------------------------
__global__ __launch_bounds__(256) void k4_reduce(
    const float* __restrict__ partial, const float* __restrict__ bc,
    float* __restrict__ out) {
  int idx = blockIdx.x * 256 + threadIdx.x;  // 25344 total
  if (idx >= B_N * NC_N) return;
  int n = idx % NC_N;
  float s = bc[n];
#pragma unroll 32
  for (int kc = 0; kc < KCH; ++kc) s += partial[(size_t)kc * (B_N * NC_N) + idx];
  out[idx] = s;
}

// ---------------------------------------------------------------------------
extern "C" void kernel_launch(void* const* d_in, const int* in_sizes, int n_in,
                              void* d_out, int out_size, void* d_ws, size_t ws_size,
                              hipStream_t stream) {
  const float* x  = (const float*)d_in[0];
  const float* Wa = (const float*)d_in[1];
  const float* ba = (const float*)d_in[2];
  const float* Wc = (const float*)d_in[3];
  const float* bc = (const float*)d_in[4];
  float* out = (float*)d_out;

  char* wsb = (char*)d_ws;
  short* Apad    = (short*)(wsb);                // 64*32*224*2    = 0.92 MB
  short* featsb  = (short*)(wsb + (1u  << 20));  // 2048*2048*2    = 8.39 MB (frag layout)
  float* zbuf    = (float*)(wsb + (10u << 20));  // 8*401408*4     = 12.85 MB (ends 22.85 MB)
  float* partial = (float*)(wsb + (23u << 20));  // 256*25344*4    = 25.95 MB (ends 48.95 MB)
  // footprint 48.95 MB < 53 MB validated in r7 (partial no longer aliases zbuf)
  (void)ws_size; (void)in_sizes; (void)n_in; (void)out_size;

  hipLaunchKernelGGL(k1a_partial, dim3(NCH, B_N), dim3(256), 0, stream,
                     x, Wa, zbuf);
  hipLaunchKernelGGL(k1b_sig, dim3(1792), dim3(256), 0, stream,
                     zbuf, ba, Apad);
  hipLaunchKernelGGL(k2_bap, dim3(32, 32), dim3(256), 0, stream,
                     x, Apad, featsb);
  hipLaunchKernelGGL(k3_cls, dim3(7, KCH), dim3(256), 0, stream,
                     featsb, Wc, partial);
  hipLaunchKernelGGL(k4_reduce, dim3(99), dim3(256), 0, stream,
                     partial, bc, out);
}